// Round 8
// baseline (6058.311 us; speedup 1.0000x reference)
//
#include <hip/hip_runtime.h>

// ---------------------------------------------------------------------------
// Persistent fused 2-layer LSTM + FC for MI355X — v8: 512-thr WGs,
// single-pass staging, fewer producers, coalesced h0 stores.
//  - Grid (24,4): per batch-group g (16 batches): 8 L0-WGs + 16 L1-WGs,
//    512 threads (8 waves) each. 1 WG/CU, launch_bounds(512,1) => 256 VGPR cap.
//  - L0 WG: wave owns 8 units full-K(576), units paired (u,u+1 per lane)
//    so the two tagged fp16 results merge into ONE u64 store.
//  - L1 WG: wave owns 4 units full-K(1024).
//  - Interlocked v6 protocol (proven): all WGs stage h0+h1 of step s-1 and
//    verify all tags==s. 64KB / 512 thr = 16 u64 loads, ONE pass (v6 had two
//    serialized passes) -> one less LLC drain per step.
//  - Exchange: u32 = fp16|(tag<<16), 3-slot agent-scope ring, speculative
//    bulk read + per-word retry. Double-buffered LDS staging, 1 barrier/step.
// ---------------------------------------------------------------------------

#define H      512
#define T_SEQ  1024
#define DIN    64
#define STEPS  1025

#define SLOT_U32 16384           // [2 layers][16 batch][512 units] tagged u32
#define GRP_U32  49152           // 3 slots
#define WS_BYTES (4 * GRP_U32 * 4)

typedef _Float16 f16x8 __attribute__((ext_vector_type(8)));
typedef float    f32x4 __attribute__((ext_vector_type(4)));
typedef unsigned long long u64t;

__device__ __forceinline__ u64t ld_u64(const u64t* p) {
  return __hip_atomic_load((u64t*)p, __ATOMIC_RELAXED, __HIP_MEMORY_SCOPE_AGENT);
}
__device__ __forceinline__ void st_u32(unsigned* p, unsigned v) {
  __hip_atomic_store(p, v, __ATOMIC_RELAXED, __HIP_MEMORY_SCOPE_AGENT);
}
__device__ __forceinline__ void st_u64(u64t* p, u64t v) {
  __hip_atomic_store(p, v, __ATOMIC_RELAXED, __HIP_MEMORY_SCOPE_AGENT);
}
__device__ __forceinline__ f16x8 pk8(float4 a, float4 b) {
  f16x8 r;
  r[0] = (_Float16)a.x; r[1] = (_Float16)a.y; r[2] = (_Float16)a.z; r[3] = (_Float16)a.w;
  r[4] = (_Float16)b.x; r[5] = (_Float16)b.y; r[6] = (_Float16)b.z; r[7] = (_Float16)b.w;
  return r;
}
__device__ __forceinline__ f16x8 cvt8(const float* p) {
  return pk8(*(const float4*)p, *(const float4*)(p + 4));
}
__device__ __forceinline__ f32x4 mfma16(f16x8 a, f16x8 b, f32x4 c) {
  return __builtin_amdgcn_mfma_f32_16x16x32_f16(a, b, c, 0, 0, 0);
}
__device__ __forceinline__ float rcpf_(float x) {
#if __has_builtin(__builtin_amdgcn_rcpf)
  return __builtin_amdgcn_rcpf(x);
#else
  return 1.0f / x;
#endif
}
__device__ __forceinline__ float sigm(float x) {
  x = fminf(fmaxf(x, -30.f), 30.f);
  return rcpf_(1.f + __expf(-x));
}
__device__ __forceinline__ float tanhx(float x) {
  x = fminf(fmaxf(x, -15.f), 15.f);
  float e = __expf(2.f * x);
  return (e - 1.f) * rcpf_(e + 1.f);
}
__device__ __forceinline__ unsigned payload(u64t v) {
  return ((unsigned)v & 0xffffu) | ((unsigned)(v >> 32) << 16);
}

__global__ __launch_bounds__(512, 1)
void lstm_fused(const float* __restrict__ x,
                const float* __restrict__ Wih0, const float* __restrict__ Whh0,
                const float* __restrict__ bih0, const float* __restrict__ bhh0,
                const float* __restrict__ Wih1, const float* __restrict__ Whh1,
                const float* __restrict__ bih1, const float* __restrict__ bhh1,
                const float* __restrict__ fcw,  const float* __restrict__ fcb,
                float* __restrict__ out, unsigned* __restrict__ ws)
{
  // double-buffered staged h: [buf][2 layers][16 batch][260 u32]
  __shared__ unsigned sH[2 * 8320];

  const int tid  = threadIdx.x;
  const int r    = blockIdx.x;          // 0..23 within group
  const int g    = blockIdx.y;          // batch group 0..3
  const int wv   = tid >> 6;            // wave 0..7
  const int lane = tid & 63;
  const int bcol = lane & 15;           // MFMA N col = batch-in-group
  const int kgrp = lane >> 4;
  const bool isL0 = (r < 8);

  unsigned* gbase = ws + g * GRP_U32;

  const int src_m = lane & 15;
  // L0: 8 units, paired mapping (tile0 = even units, tile1 = odd units)
  // L1: 4 units, plain mapping
  const int hb = isL0 ? (r * 64 + wv * 8) : ((r - 8) * 32 + wv * 4);

  // ---- resident weight A-fragments
  f16x8 wA[36];
  if (isL0) {
    const int gr0 = (src_m & 3) * H + hb + 2 * (src_m >> 2); // even unit row
    const int gr1 = gr0 + 1;                                 // odd unit row
    #pragma unroll
    for (int f = 0; f < 18; ++f) {      // K = 64(x) + 512(h0)
      const float *p0, *p1;
      if (f < 2) {
        p0 = Wih0 + (size_t)gr0 * DIN + f * 32 + kgrp * 8;
        p1 = Wih0 + (size_t)gr1 * DIN + f * 32 + kgrp * 8;
      } else {
        p0 = Whh0 + (size_t)gr0 * H + (f - 2) * 32 + kgrp * 8;
        p1 = Whh0 + (size_t)gr1 * H + (f - 2) * 32 + kgrp * 8;
      }
      wA[f] = cvt8(p0); wA[18 + f] = cvt8(p1);
    }
  } else {
    const int gr0 = (src_m & 3) * H + hb + (src_m >> 2);
    #pragma unroll
    for (int f = 0; f < 16; ++f)        // Wih1 (h0 half)
      wA[f] = cvt8(Wih1 + (size_t)gr0 * H + f * 32 + kgrp * 8);
    #pragma unroll
    for (int f = 0; f < 16; ++f)        // Whh1 (h1 half)
      wA[16 + f] = cvt8(Whh1 + (size_t)gr0 * H + f * 32 + kgrp * 8);
  }
  float bias0[4], bias1[4];
  {
    const float* bi = isL0 ? bih0 : bih1;
    const float* bh = isL0 ? bhh0 : bhh1;
    const int u0 = isL0 ? (hb + 2 * kgrp) : (hb + kgrp);
    const int u1 = isL0 ? (hb + 2 * kgrp + 1) : 0;
    #pragma unroll
    for (int rr = 0; rr < 4; ++rr) {
      bias0[rr] = bi[rr * H + u0] + bh[rr * H + u0];
      bias1[rr] = isL0 ? (bi[rr * H + u1] + bh[rr * H + u1]) : 0.f;
    }
  }

  // zero both staging buffers once (step 0 reads zeros as h_{-1})
  for (int i = tid; i < 2 * 8320; i += 512) sH[i] = 0;
  __syncthreads();

  float c0 = 0.f, c1 = 0.f;
  unsigned spins = 0;
  const int rowb = bcol * 1040 + kgrp * 16;   // byte offset of B-frag row

  for (int s = 0; s < STEPS; ++s) {
    // ---- single-pass bulk read of tag-s data (64 KB, 16 u64/thread)
    if (s > 0) {
      const u64t* src = (const u64t*)(gbase + ((s - 1) % 3) * SLOT_U32);
      const unsigned want = (unsigned)s;
      u64t v[16];
      #pragma unroll
      for (int i = 0; i < 16; ++i) v[i] = ld_u64(src + tid + i * 512);
      for (;;) {
        unsigned bad = 0;
        #pragma unroll
        for (int i = 0; i < 16; ++i) {
          unsigned lo = (unsigned)v[i], hi = (unsigned)(v[i] >> 32);
          if (((lo >> 16) ^ want) | ((hi >> 16) ^ want)) bad |= (1u << i);
        }
        if (!bad) break;
        if (++spins > 8000000u) break;         // bounded anti-hang guard
        #pragma unroll
        for (int i = 0; i < 16; ++i)
          if (bad & (1u << i)) v[i] = ld_u64(src + tid + i * 512);
      }
      unsigned* db = sH + (s & 1) * 8320;
      #pragma unroll
      for (int i = 0; i < 16; ++i) {
        int j = tid + i * 512;                 // [2][16][256] u64 index
        db[(j >> 12) * 4160 + ((j >> 8) & 15) * 260 + (j & 255)] = payload(v[i]);
      }
    }
    // x prefetch for L0 (frags 0,1) — issued after ring loads (non-critical)
    float4 xr0 = {0,0,0,0}, xr1 = xr0, xr2 = xr0, xr3 = xr0;
    if (isL0) {
      int t = (s < T_SEQ) ? s : (T_SEQ - 1);
      const float* xp = x + ((size_t)((g * 16 + bcol) * T_SEQ + t)) * DIN + kgrp * 8;
      xr0 = *(const float4*)xp;        xr1 = *(const float4*)(xp + 4);
      xr2 = *(const float4*)(xp + 32); xr3 = *(const float4*)(xp + 36);
    }
    __syncthreads();                           // staged (dbuf handles WAR)

    const bool act = isL0 ? (s < T_SEQ) : (s > 0);
    const char* cur = (const char*)(sH + (s & 1) * 8320);
    if (isL0) {
      float hv0 = 0.f, hv1 = 0.f;
      if (act) {
        f32x4 a0 = {0,0,0,0}, a1 = {0,0,0,0};
        f16x8 b0 = pk8(xr0, xr1);
        a0 = mfma16(wA[0], b0, a0); a1 = mfma16(wA[18], b0, a1);
        f16x8 b1 = pk8(xr2, xr3);
        a0 = mfma16(wA[1], b1, a0); a1 = mfma16(wA[19], b1, a1);
        #pragma unroll
        for (int f = 2; f < 18; ++f) {
          f16x8 bf = *(const f16x8*)(cur + rowb + (f - 2) * 64);
          a0 = mfma16(wA[f], bf, a0); a1 = mfma16(wA[18 + f], bf, a1);
        }
        {
          float ii = sigm(a0[0] + bias0[0]);
          float ff = sigm(a0[1] + bias0[1]);
          float gg = tanhx(a0[2] + bias0[2]);
          float oo = sigm(a0[3] + bias0[3]);
          c0 = ff * c0 + ii * gg;  hv0 = oo * tanhx(c0);
        }
        {
          float ii = sigm(a1[0] + bias1[0]);
          float ff = sigm(a1[1] + bias1[1]);
          float gg = tanhx(a1[2] + bias1[2]);
          float oo = sigm(a1[3] + bias1[3]);
          c1 = ff * c1 + ii * gg;  hv1 = oo * tanhx(c1);
        }
      }
      if (s < T_SEQ) {                         // produce h0(s), tag s+1
        u64t tag = (u64t)((unsigned)(s + 1) << 16);
        u64t w0 = tag | (u64t)(unsigned short)__builtin_bit_cast(unsigned short, (_Float16)hv0);
        u64t w1 = tag | (u64t)(unsigned short)__builtin_bit_cast(unsigned short, (_Float16)hv1);
        u64t* dst = (u64t*)(gbase + (s % 3) * SLOT_U32 + bcol * 512 + hb) + kgrp;
        st_u64(dst, w0 | (w1 << 32));          // units hb+2k, hb+2k+1
      }
    } else {
      float hv = 0.f;
      if (act) {
        f32x4 a0 = {0,0,0,0}, a1 = {0,0,0,0};
        #pragma unroll
        for (int f = 0; f < 16; ++f) {         // Wih1 * h0(s-1)
          f16x8 bf = *(const f16x8*)(cur + rowb + f * 64);
          if (f & 1) a1 = mfma16(wA[f], bf, a1); else a0 = mfma16(wA[f], bf, a0);
        }
        #pragma unroll
        for (int f = 0; f < 16; ++f) {         // Whh1 * h1(s-2)
          f16x8 bf = *(const f16x8*)(cur + 16640 + rowb + f * 64);
          if (f & 1) a1 = mfma16(wA[16 + f], bf, a1); else a0 = mfma16(wA[16 + f], bf, a0);
        }
        f32x4 a = a0 + a1;
        float ii = sigm(a[0] + bias0[0]);
        float ff = sigm(a[1] + bias0[1]);
        float gg = tanhx(a[2] + bias0[2]);
        float oo = sigm(a[3] + bias0[3]);
        c0 = ff * c0 + ii * gg;
        hv = oo * tanhx(c0);
      }
      {                                        // produce h1(s-1), tag s+1
        unsigned tag = (unsigned)(s + 1) << 16;
        unsigned hu = (unsigned)__builtin_bit_cast(unsigned short, (_Float16)hv);
        unsigned* dst = gbase + (s % 3) * SLOT_U32 + 8192 + bcol * 512 + hb + kgrp;
        st_u32(dst, hu | tag);
      }
    }
  }

  __syncthreads();                             // main-loop LDS reads done

  // ---- FC epilogue: out = relu([h0_T; h1_T] @ fc_w^T + fc_b), [128][1024]
  // 64 WGs x 2 col-tiles each; waves 0-3 -> ct0, waves 4-7 -> ct1.
  const int fid = g * 24 + r;
  if (fid < 64) {
    const int rt = fid >> 3;                   // 0..7 (4 groups x 2 layers)
    const int sg = rt & 3;
    const bool isH1 = (rt >= 4);
    // h0_T = h0(1023): slot 1023%3=0, tag 1024; h1_T: step 1024 -> slot 1, tag 1025
    const unsigned want = isH1 ? (unsigned)STEPS : (unsigned)(STEPS - 1);
    const int     slot  = isH1 ? 1 : 0;
    const u64t* src = (const u64t*)(ws + sg * GRP_U32 + slot * SLOT_U32
                                    + (isH1 ? 8192 : 0));
    u64t v[8];
    #pragma unroll
    for (int i = 0; i < 8; ++i) v[i] = ld_u64(src + tid + i * 512);
    for (;;) {
      unsigned bad = 0;
      #pragma unroll
      for (int i = 0; i < 8; ++i) {
        unsigned lo = (unsigned)v[i], hi = (unsigned)(v[i] >> 32);
        if (((lo >> 16) ^ want) | ((hi >> 16) ^ want)) bad |= (1u << i);
      }
      if (!bad) break;
      if (++spins > 8000000u) break;
      #pragma unroll
      for (int i = 0; i < 8; ++i)
        if (bad & (1u << i)) v[i] = ld_u64(src + tid + i * 512);
    }
    #pragma unroll
    for (int i = 0; i < 8; ++i) {
      int j = tid + i * 512;                   // [16 batch][256 pairs]
      sH[(j >> 8) * 260 + (j & 255)] = payload(v[i]);
    }
    __syncthreads();
    const int ct  = (fid & 7) * 2 + (wv >> 2);
    const int col = ct * 64 + (wv & 3) * 16 + bcol;
    f32x4 a0 = {0,0,0,0}, a1 = {0,0,0,0};
    #pragma unroll
    for (int f = 0; f < 16; ++f) {             // K = 512
      f16x8 af = *(const f16x8*)((const char*)sH + rowb + f * 64);
      f16x8 bf = cvt8(fcw + (size_t)col * H + f * 32 + kgrp * 8);
      if (f & 1) a1 = mfma16(af, bf, a1); else a0 = mfma16(af, bf, a0);
    }
    f32x4 a = a0 + a1;
    const float fb = fcb[col];
    #pragma unroll
    for (int rr = 0; rr < 4; ++rr) {
      int row = rt * 16 + kgrp * 4 + rr;
      float v2 = a[rr] + fb;
      out[(size_t)row * 1024 + col] = v2 > 0.f ? v2 : 0.f;
    }
  }
}

extern "C" void kernel_launch(void* const* d_in, const int* in_sizes, int n_in,
                              void* d_out, int out_size, void* d_ws, size_t ws_size,
                              hipStream_t stream) {
  const float* x    = (const float*)d_in[0];
  const float* Wih0 = (const float*)d_in[1];
  const float* Whh0 = (const float*)d_in[2];
  const float* bih0 = (const float*)d_in[3];
  const float* bhh0 = (const float*)d_in[4];
  const float* Wih1 = (const float*)d_in[5];
  const float* Whh1 = (const float*)d_in[6];
  const float* bih1 = (const float*)d_in[7];
  const float* bhh1 = (const float*)d_in[8];
  const float* fcw  = (const float*)d_in[9];
  const float* fcb  = (const float*)d_in[10];
  (void)in_sizes; (void)n_in; (void)out_size; (void)ws_size;

  // zero tag space every call (tag 0 never matches any wanted tag >= 1)
  hipMemsetAsync(d_ws, 0, WS_BYTES, stream);
  lstm_fused<<<dim3(24, 4), dim3(512), 0, stream>>>(
      x, Wih0, Whh0, bih0, bhh0, Wih1, Whh1, bih1, bhh1, fcw, fcb,
      (float*)d_out, (unsigned*)d_ws);
}

// Round 9
// 4645.832 us; speedup vs baseline: 1.3040x; 1.3040x over previous
//
#include <hip/hip_runtime.h>

// ---------------------------------------------------------------------------
// Persistent fused 2-layer LSTM + FC for MI355X — v9: 8 groups x 8 batches.
//  - Grid (32,8): 256 WGs x 256 thr (1/CU), v6 wave roles preserved:
//      wv0/wv1: L0 units [hb,hb+8), full-K 576 (x + h0)
//      wv2/wv3: L1 units [hb,hb+8), full-K 1024 (h0 + h1)
//    hb = r*16 + (wv&1)*8. Weights resident (v6's proven 204-VGPR envelope;
//    256-thr WGs — 512-thr WGs get a 128-VGPR cap and spill: v4/v8 lesson).
//  - Ring slot now [2 layers][8 batch][512 units] = 32KB: staging is ONE
//    16-load drain (v6 had two serialized 16-load passes over 64KB).
//  - MFMA N=16 with 8 valid batch cols (cols 8-15 discarded; B rows 8-15
//    stay zero in LDS). Compute is ~8% of step; latency is what matters.
//  - Exchange protocol byte-for-byte v6: u32 = fp16|(tag<<16), 3-slot
//    agent-scope ring, speculative bulk read + per-word retry, double-
//    buffered LDS staging, 1 barrier/step.
// ---------------------------------------------------------------------------

#define H      512
#define T_SEQ  1024
#define DIN    64
#define STEPS  1025

#define SLOT_U32 8192            // [2 layers][8 batch][512 units] tagged u32
#define GRP_U32  24576           // 3 slots
#define WS_BYTES (8 * GRP_U32 * 4)

typedef _Float16 f16x8 __attribute__((ext_vector_type(8)));
typedef float    f32x4 __attribute__((ext_vector_type(4)));
typedef unsigned long long u64t;

__device__ __forceinline__ u64t ld_u64(const u64t* p) {
  return __hip_atomic_load((u64t*)p, __ATOMIC_RELAXED, __HIP_MEMORY_SCOPE_AGENT);
}
__device__ __forceinline__ void st_u32(unsigned* p, unsigned v) {
  __hip_atomic_store(p, v, __ATOMIC_RELAXED, __HIP_MEMORY_SCOPE_AGENT);
}
__device__ __forceinline__ f16x8 pk8(float4 a, float4 b) {
  f16x8 r;
  r[0] = (_Float16)a.x; r[1] = (_Float16)a.y; r[2] = (_Float16)a.z; r[3] = (_Float16)a.w;
  r[4] = (_Float16)b.x; r[5] = (_Float16)b.y; r[6] = (_Float16)b.z; r[7] = (_Float16)b.w;
  return r;
}
__device__ __forceinline__ f16x8 cvt8(const float* p) {
  return pk8(*(const float4*)p, *(const float4*)(p + 4));
}
__device__ __forceinline__ f32x4 mfma16(f16x8 a, f16x8 b, f32x4 c) {
  return __builtin_amdgcn_mfma_f32_16x16x32_f16(a, b, c, 0, 0, 0);
}
__device__ __forceinline__ float rcpf_(float x) {
#if __has_builtin(__builtin_amdgcn_rcpf)
  return __builtin_amdgcn_rcpf(x);
#else
  return 1.0f / x;
#endif
}
__device__ __forceinline__ float sigm(float x) {
  x = fminf(fmaxf(x, -30.f), 30.f);
  return rcpf_(1.f + __expf(-x));
}
__device__ __forceinline__ float tanhx(float x) {
  x = fminf(fmaxf(x, -15.f), 15.f);
  float e = __expf(2.f * x);
  return (e - 1.f) * rcpf_(e + 1.f);
}
__device__ __forceinline__ unsigned payload(u64t v) {
  return ((unsigned)v & 0xffffu) | ((unsigned)(v >> 32) << 16);
}

__global__ __launch_bounds__(256, 1)
void lstm_fused(const float* __restrict__ x,
                const float* __restrict__ Wih0, const float* __restrict__ Whh0,
                const float* __restrict__ bih0, const float* __restrict__ bhh0,
                const float* __restrict__ Wih1, const float* __restrict__ Whh1,
                const float* __restrict__ bih1, const float* __restrict__ bhh1,
                const float* __restrict__ fcw,  const float* __restrict__ fcb,
                float* __restrict__ out, unsigned* __restrict__ ws)
{
  // double-buffered staged h: [buf][2 layers][16 rows][260 u32]
  // (rows 8-15 of each layer region stay zero — fake MFMA columns)
  __shared__ unsigned sH[2][8320];

  const int tid  = threadIdx.x;
  const int r    = blockIdx.x;         // 0..31 within group
  const int g    = blockIdx.y;         // batch group 0..7 (8 batches)
  const int wv   = tid >> 6;           // wave 0..3
  const int lane = tid & 63;
  const int bcol = lane & 15;          // MFMA N col; batches = cols 0..7
  const int kgrp = lane >> 4;
  const int layer = wv >> 1;
  const int hb    = r * 16 + (wv & 1) * 8;   // 8 units of this wave

  unsigned* gbase = ws + g * GRP_U32;

  // ---- resident weights: 2 M-tiles (units hb..+3, hb+4..+7), full K.
  //      M rows gate-interleaved: row m -> gate m&3, unit hb + (m>>2).
  const int src_m = lane & 15;
  const int gr0 = (src_m & 3) * H + hb + (src_m >> 2);   // PyTorch gate row
  const int gr1 = gr0 + 4;
  f16x8 wA[2][32];
  if (layer == 0) {                    // K = 64(x) + 512(h0): frags 0..17
    #pragma unroll
    for (int f = 0; f < 18; ++f) {
      const float *p0, *p1;
      if (f < 2) {
        p0 = Wih0 + (size_t)gr0 * DIN + f * 32 + kgrp * 8;
        p1 = Wih0 + (size_t)gr1 * DIN + f * 32 + kgrp * 8;
      } else {
        p0 = Whh0 + (size_t)gr0 * H + (f - 2) * 32 + kgrp * 8;
        p1 = Whh0 + (size_t)gr1 * H + (f - 2) * 32 + kgrp * 8;
      }
      wA[0][f] = cvt8(p0); wA[1][f] = cvt8(p1);
    }
  } else {                             // K = 512(h0) + 512(h1): frags 0..31
    #pragma unroll
    for (int f = 0; f < 16; ++f) {
      int col = f * 32 + kgrp * 8;
      wA[0][f] = cvt8(Wih1 + (size_t)gr0 * H + col);
      wA[1][f] = cvt8(Wih1 + (size_t)gr1 * H + col);
    }
    #pragma unroll
    for (int f = 16; f < 32; ++f) {
      int col = (f - 16) * 32 + kgrp * 8;
      wA[0][f] = cvt8(Whh1 + (size_t)gr0 * H + col);
      wA[1][f] = cvt8(Whh1 + (size_t)gr1 * H + col);
    }
  }
  float bias[2][4];
  {
    const float* bi = layer ? bih1 : bih0;
    const float* bh = layer ? bhh1 : bhh0;
    #pragma unroll
    for (int t = 0; t < 2; ++t)
      #pragma unroll
      for (int rr = 0; rr < 4; ++rr) {
        int u = hb + t * 4 + kgrp;
        bias[t][rr] = bi[rr * H + u] + bh[rr * H + u];
      }
  }

  // zero both staging buffers once (step 0 reads zeros as h_{-1};
  // rows 8-15 stay zero forever)
  for (int i = tid; i < 2 * 8320; i += 256) ((unsigned*)sH)[i] = 0;
  __syncthreads();

  float cst0 = 0.f, cst1 = 0.f;
  unsigned spins = 0;
  const int rowb = bcol * 1040 + kgrp * 16;   // byte offset of B-frag row

  for (int s = 0; s < STEPS; ++s) {
    // x prefetch for L0 waves (frags 0,1); fake cols duplicate batch 0
    float4 xr0 = {0,0,0,0}, xr1 = xr0, xr2 = xr0, xr3 = xr0;
    if (layer == 0) {
      int t = (s < T_SEQ) ? s : (T_SEQ - 1);
      int b = g * 8 + (bcol & 7);
      const float* xp = x + ((size_t)(b * T_SEQ + t)) * DIN + kgrp * 8;
      xr0 = *(const float4*)xp;        xr1 = *(const float4*)(xp + 4);
      xr2 = *(const float4*)(xp + 32); xr3 = *(const float4*)(xp + 36);
    }
    // single-pass bulk read of tag-s data (32KB, 16 u64/thread) + retry
    if (s > 0) {
      const u64t* src = (const u64t*)(gbase + ((s - 1) % 3) * SLOT_U32);
      const unsigned want = (unsigned)s;
      u64t v[16];
      #pragma unroll
      for (int i = 0; i < 16; ++i) v[i] = ld_u64(src + tid + i * 256);
      for (;;) {
        unsigned bad = 0;
        #pragma unroll
        for (int i = 0; i < 16; ++i) {
          unsigned lo = (unsigned)v[i], hi = (unsigned)(v[i] >> 32);
          if (((lo >> 16) ^ want) | ((hi >> 16) ^ want)) bad |= (1u << i);
        }
        if (!bad) break;
        if (++spins > 8000000u) break;         // bounded anti-hang guard
        #pragma unroll
        for (int i = 0; i < 16; ++i)
          if (bad & (1u << i)) v[i] = ld_u64(src + tid + i * 256);
      }
      unsigned* db = sH[s & 1];
      #pragma unroll
      for (int i = 0; i < 16; ++i) {
        int j = tid + i * 256;                 // [2][8][256] u64 index
        db[(j >> 11) * 4160 + ((j >> 8) & 7) * 260 + (j & 255)] = payload(v[i]);
      }
    }
    __syncthreads();                           // staged; WAR handled by dbuf

    const bool act = layer ? (s > 0) : (s < T_SEQ);
    float hv0 = 0.f, hv1 = 0.f;
    if (act) {
      f32x4 acc0 = {0,0,0,0}, acc1 = {0,0,0,0};
      const char* cur = (const char*)sH[s & 1];
      if (layer == 0) {
        f16x8 b0 = pk8(xr0, xr1);
        acc0 = mfma16(wA[0][0], b0, acc0); acc1 = mfma16(wA[1][0], b0, acc1);
        f16x8 b1 = pk8(xr2, xr3);
        acc0 = mfma16(wA[0][1], b1, acc0); acc1 = mfma16(wA[1][1], b1, acc1);
        #pragma unroll
        for (int f = 2; f < 18; ++f) {
          f16x8 bf = *(const f16x8*)(cur + rowb + (f - 2) * 64);
          acc0 = mfma16(wA[0][f], bf, acc0); acc1 = mfma16(wA[1][f], bf, acc1);
        }
      } else {
        #pragma unroll
        for (int f = 0; f < 16; ++f) {
          f16x8 bf = *(const f16x8*)(cur + rowb + f * 64);
          acc0 = mfma16(wA[0][f], bf, acc0); acc1 = mfma16(wA[1][f], bf, acc1);
        }
        #pragma unroll
        for (int f = 16; f < 32; ++f) {
          f16x8 bf = *(const f16x8*)(cur + 16640 + rowb + (f - 16) * 64);
          acc0 = mfma16(wA[0][f], bf, acc0); acc1 = mfma16(wA[1][f], bf, acc1);
        }
      }
      {
        float ii = sigm(acc0[0] + bias[0][0]);
        float ff = sigm(acc0[1] + bias[0][1]);
        float gg = tanhx(acc0[2] + bias[0][2]);
        float oo = sigm(acc0[3] + bias[0][3]);
        cst0 = ff * cst0 + ii * gg;
        hv0 = oo * tanhx(cst0);
      }
      {
        float ii = sigm(acc1[0] + bias[1][0]);
        float ff = sigm(acc1[1] + bias[1][1]);
        float gg = tanhx(acc1[2] + bias[1][2]);
        float oo = sigm(acc1[3] + bias[1][3]);
        cst1 = ff * cst1 + ii * gg;
        hv1 = oo * tanhx(cst1);
      }
    }
    const bool produce = layer ? true : (s < T_SEQ);   // L1 emits zeros at s=0
    if (produce && bcol < 8) {
      unsigned tag = (unsigned)(s + 1) << 16;
      unsigned u0 = (unsigned)__builtin_bit_cast(unsigned short, (_Float16)hv0);
      unsigned u1 = (unsigned)__builtin_bit_cast(unsigned short, (_Float16)hv1);
      unsigned* dst = gbase + (s % 3) * SLOT_U32 + layer * 4096
                    + bcol * 512 + hb + kgrp;
      st_u32(dst,     u0 | tag);               // unit hb+kgrp
      st_u32(dst + 4, u1 | tag);               // unit hb+kgrp+4
    }
    // no trailing barrier: next step writes the OTHER LDS buffer
  }

  __syncthreads();                             // main-loop LDS reads done

  // ---- FC epilogue: out = relu([h0_T; h1_T] @ fc_w^T + fc_b), [128][1024]
  const int fid = g * 32 + r;
  if (fid < 128) {
    const int rt = fid >> 4, ct = fid & 15;    // 8 row-tiles x 16 col-tiles
    const bool isH1 = (rt >= 4);
    // h0_T = h0(1023): slot 1023%3=0, tag 1024; h1_T: step 1024 -> slot 1, tag 1025
    const unsigned want = isH1 ? (unsigned)STEPS : (unsigned)(STEPS - 1);
    const int     slot  = isH1 ? 1 : 0;
    const int     bt    = rt & 3;              // batch-tile: batches [bt*16, +16)
    u64t v[16];
    #pragma unroll
    for (int i = 0; i < 16; ++i) {
      int j = tid + i * 256;                   // [16 rows][256 pairs]
      int row = j >> 8, pair = j & 255;
      int gg = bt * 2 + (row >> 3);            // source group
      const u64t* sp = (const u64t*)(ws + gg * GRP_U32 + slot * SLOT_U32
                                     + (isH1 ? 4096 : 0));
      v[i] = ld_u64(sp + (row & 7) * 256 + pair);
    }
    for (;;) {
      unsigned bad = 0;
      #pragma unroll
      for (int i = 0; i < 16; ++i) {
        unsigned lo = (unsigned)v[i], hi = (unsigned)(v[i] >> 32);
        if (((lo >> 16) ^ want) | ((hi >> 16) ^ want)) bad |= (1u << i);
      }
      if (!bad) break;
      if (++spins > 8000000u) break;
      #pragma unroll
      for (int i = 0; i < 16; ++i)
        if (bad & (1u << i)) {
          int j = tid + i * 256;
          int row = j >> 8, pair = j & 255;
          int gg = bt * 2 + (row >> 3);
          const u64t* sp = (const u64t*)(ws + gg * GRP_U32 + slot * SLOT_U32
                                         + (isH1 ? 4096 : 0));
          v[i] = ld_u64(sp + (row & 7) * 256 + pair);
        }
    }
    #pragma unroll
    for (int i = 0; i < 16; ++i) {
      int j = tid + i * 256;
      sH[0][(j >> 8) * 260 + (j & 255)] = payload(v[i]);
    }
    __syncthreads();
    const int col = ct * 64 + wv * 16 + bcol;
    f32x4 a0 = {0,0,0,0}, a1 = {0,0,0,0};
    #pragma unroll
    for (int f = 0; f < 16; ++f) {             // K = 512
      f16x8 af = *(const f16x8*)((const char*)sH[0] + rowb + f * 64);
      f16x8 bf = cvt8(fcw + (size_t)col * H + f * 32 + kgrp * 8);
      if (f & 1) a1 = mfma16(af, bf, a1); else a0 = mfma16(af, bf, a0);
    }
    f32x4 a = a0 + a1;
    const float fb = fcb[col];
    #pragma unroll
    for (int rr = 0; rr < 4; ++rr) {
      int row = rt * 16 + kgrp * 4 + rr;
      float v2 = a[rr] + fb;
      out[(size_t)row * 1024 + col] = v2 > 0.f ? v2 : 0.f;
    }
  }
}

extern "C" void kernel_launch(void* const* d_in, const int* in_sizes, int n_in,
                              void* d_out, int out_size, void* d_ws, size_t ws_size,
                              hipStream_t stream) {
  const float* x    = (const float*)d_in[0];
  const float* Wih0 = (const float*)d_in[1];
  const float* Whh0 = (const float*)d_in[2];
  const float* bih0 = (const float*)d_in[3];
  const float* bhh0 = (const float*)d_in[4];
  const float* Wih1 = (const float*)d_in[5];
  const float* Whh1 = (const float*)d_in[6];
  const float* bih1 = (const float*)d_in[7];
  const float* bhh1 = (const float*)d_in[8];
  const float* fcw  = (const float*)d_in[9];
  const float* fcb  = (const float*)d_in[10];
  (void)in_sizes; (void)n_in; (void)out_size; (void)ws_size;

  // zero tag space every call (tag 0 never matches any wanted tag >= 1)
  hipMemsetAsync(d_ws, 0, WS_BYTES, stream);
  lstm_fused<<<dim3(32, 8), dim3(256), 0, stream>>>(
      x, Wih0, Whh0, bih0, bhh0, Wih1, Whh1, bih1, bhh1, fcw, fcb,
      (float*)d_out, (unsigned*)d_ws);
}